// Round 1
// baseline (665.969 us; speedup 1.0000x reference)
//
#include <hip/hip_runtime.h>
#include <hip/hip_bf16.h>

typedef unsigned short u16;
typedef short short8 __attribute__((ext_vector_type(8)));
typedef float f32x4 __attribute__((ext_vector_type(4)));

#define B_ROWS 8192
#define D_DIM  1024

// ---------------------------------------------------------------------------
// Workspace layout (bytes):
//   [0, 32768)            rowsum[8192]  (float)  -- zeroed by memset
//   [32768, 32784)        scal[3]: mse_q, mse_p, diag  -- zeroed by memset
//   [65536, +16MiB)       qn bf16 [8192][1024]
//   [65536+16MiB, +16MiB) pn bf16 [8192][1024]
// ---------------------------------------------------------------------------

__device__ __forceinline__ u16 f2bf(float x) {
    union { float f; unsigned u; } v; v.f = x;
    unsigned r = v.u + 0x7fffu + ((v.u >> 16) & 1u);  // RNE
    return (u16)(r >> 16);
}

// ---------------------------------------------------------------------------
// Kernel 1: per-row norms, MSE partials, diag partial, bf16 normalized writes
// grid = 8192 blocks of 256 threads; each thread owns one float4 (D/4 = 256)
// ---------------------------------------------------------------------------
__global__ void __launch_bounds__(256) prep_kernel(
    const float* __restrict__ sq, const float* __restrict__ sp,
    const float* __restrict__ tq, const float* __restrict__ tp,
    u16* __restrict__ qn, u16* __restrict__ pn,
    float* __restrict__ scal)
{
    const int r = blockIdx.x;
    const int t = threadIdx.x;
    const size_t base4 = (size_t)r * (D_DIM / 4) + t;

    const float4 q = ((const float4*)sq)[base4];
    const float4 p = ((const float4*)sp)[base4];
    const float4 a = ((const float4*)tq)[base4];
    const float4 b = ((const float4*)tp)[base4];

    float sq2 = q.x*q.x + q.y*q.y + q.z*q.z + q.w*q.w;
    float sp2 = p.x*p.x + p.y*p.y + p.z*p.z + p.w*p.w;
    float dqx = q.x-a.x, dqy = q.y-a.y, dqz = q.z-a.z, dqw = q.w-a.w;
    float dq  = dqx*dqx + dqy*dqy + dqz*dqz + dqw*dqw;
    float dpx = p.x-b.x, dpy = p.y-b.y, dpz = p.z-b.z, dpw = p.w-b.w;
    float dp  = dpx*dpx + dpy*dpy + dpz*dpz + dpw*dpw;
    float qp  = q.x*p.x + q.y*p.y + q.z*p.z + q.w*p.w;

    // wave64 butterfly reduce (5 values)
    #pragma unroll
    for (int m = 1; m <= 32; m <<= 1) {
        sq2 += __shfl_xor(sq2, m);
        sp2 += __shfl_xor(sp2, m);
        dq  += __shfl_xor(dq, m);
        dp  += __shfl_xor(dp, m);
        qp  += __shfl_xor(qp, m);
    }

    __shared__ float red[4][5];
    __shared__ float bc[2];
    const int wave = t >> 6, lane = t & 63;
    if (lane == 0) {
        red[wave][0] = sq2; red[wave][1] = sp2;
        red[wave][2] = dq;  red[wave][3] = dp; red[wave][4] = qp;
    }
    __syncthreads();
    if (t == 0) {
        float S0 = 0, S1 = 0, S2 = 0, S3 = 0, S4 = 0;
        #pragma unroll
        for (int w = 0; w < 4; ++w) {
            S0 += red[w][0]; S1 += red[w][1]; S2 += red[w][2];
            S3 += red[w][3]; S4 += red[w][4];
        }
        float rinvq = 1.0f / fmaxf(sqrtf(S0), 1e-8f);
        float rinvp = 1.0f / fmaxf(sqrtf(S1), 1e-8f);
        bc[0] = rinvq; bc[1] = rinvp;
        atomicAdd(&scal[0], S2);
        atomicAdd(&scal[1], S3);
        atomicAdd(&scal[2], S4 * rinvq * rinvp);   // exact fp32 diagonal
    }
    __syncthreads();
    const float rq = bc[0], rp = bc[1];

    ushort4 qo, po;
    qo.x = f2bf(q.x * rq); qo.y = f2bf(q.y * rq);
    qo.z = f2bf(q.z * rq); qo.w = f2bf(q.w * rq);
    po.x = f2bf(p.x * rp); po.y = f2bf(p.y * rp);
    po.z = f2bf(p.z * rp); po.w = f2bf(p.w * rp);
    ((ushort4*)qn)[base4] = qo;
    ((ushort4*)pn)[base4] = po;
}

// ---------------------------------------------------------------------------
// Kernel 2: S = Qn @ Pn^T (bf16 MFMA 16x16x32), epilogue exp + row-sum
// 128x128 tile per block, BK=64, 256 threads = 4 waves in 2x2 arrangement.
// LDS chunk XOR-swizzle: LDS[row][c] holds global k-chunk (c ^ (row&7)).
// ---------------------------------------------------------------------------
__global__ void __launch_bounds__(256) gemm_rowsum_kernel(
    const u16* __restrict__ Q, const u16* __restrict__ P,
    float* __restrict__ rowsum)
{
    __shared__ u16 smA[128 * 64];   // 16 KiB, row stride 64 elems (128 B)
    __shared__ u16 smB[128 * 64];

    const int tid  = threadIdx.x;
    const int wave = tid >> 6;
    const int lane = tid & 63;
    const int bm = blockIdx.y;
    const int bn = blockIdx.x;

    // staging: each global_load_lds covers 8 rows x 64 k-elems (1 KiB)
    const int lrow   = lane >> 3;               // row within 8-row chunk
    const int gchunk = (lane & 7) ^ lrow;       // XOR swizzle of 16B k-chunks
    const u16* Ag = Q + ((size_t)bm * 128) * D_DIM + gchunk * 8;
    const u16* Bg = P + ((size_t)bn * 128) * D_DIM + gchunk * 8;

    const int quad  = lane >> 4;
    const int rw    = lane & 15;
    const int swz   = lane & 7;                 // == row&7 for fragment rows
    const int arow0 = (wave >> 1) * 64;         // wave's row strip in tile
    const int bcol0 = (wave & 1) * 64;          // wave's col strip in tile

    f32x4 acc[4][4];
    #pragma unroll
    for (int i = 0; i < 4; ++i)
        #pragma unroll
        for (int j = 0; j < 4; ++j)
            acc[i][j] = (f32x4){0.f, 0.f, 0.f, 0.f};

    for (int k0 = 0; k0 < D_DIM; k0 += 64) {
        #pragma unroll
        for (int i = 0; i < 4; ++i) {
            const int r0 = wave * 32 + i * 8;
            __builtin_amdgcn_global_load_lds(
                (const __attribute__((address_space(1))) void*)(Ag + (size_t)(r0 + lrow) * D_DIM + k0),
                (__attribute__((address_space(3))) void*)(smA + r0 * 64), 16, 0, 0);
            __builtin_amdgcn_global_load_lds(
                (const __attribute__((address_space(1))) void*)(Bg + (size_t)(r0 + lrow) * D_DIM + k0),
                (__attribute__((address_space(3))) void*)(smB + r0 * 64), 16, 0, 0);
        }
        __syncthreads();

        #pragma unroll
        for (int kk = 0; kk < 2; ++kk) {
            const int kb = kk * 4;
            const int ch = (((kb + quad) ^ swz)) * 8;   // element offset in row
            short8 afrag[4], bfrag[4];
            #pragma unroll
            for (int mi = 0; mi < 4; ++mi)
                afrag[mi] = *(const short8*)(smA + (arow0 + mi * 16 + rw) * 64 + ch);
            #pragma unroll
            for (int ni = 0; ni < 4; ++ni)
                bfrag[ni] = *(const short8*)(smB + (bcol0 + ni * 16 + rw) * 64 + ch);
            #pragma unroll
            for (int mi = 0; mi < 4; ++mi)
                #pragma unroll
                for (int ni = 0; ni < 4; ++ni)
                    acc[mi][ni] = __builtin_amdgcn_mfma_f32_16x16x32_bf16(
                        afrag[mi], bfrag[ni], acc[mi][ni], 0, 0, 0);
        }
        __syncthreads();
    }

    // epilogue: per-row sum of exp over this block's 128 columns.
    // C/D layout: col = lane&15, row = quad*4 + reg  (within each 16x16 tile)
    float esum[4][4];
    #pragma unroll
    for (int mi = 0; mi < 4; ++mi)
        #pragma unroll
        for (int r = 0; r < 4; ++r) {
            float s = 0.f;
            #pragma unroll
            for (int ni = 0; ni < 4; ++ni) s += __expf(acc[mi][ni][r]);
            esum[mi][r] = s;
        }
    #pragma unroll
    for (int m = 1; m <= 8; m <<= 1)
        #pragma unroll
        for (int mi = 0; mi < 4; ++mi)
            #pragma unroll
            for (int r = 0; r < 4; ++r)
                esum[mi][r] += __shfl_xor(esum[mi][r], m);

    if (rw == 0) {
        #pragma unroll
        for (int mi = 0; mi < 4; ++mi)
            #pragma unroll
            for (int r = 0; r < 4; ++r)
                atomicAdd(&rowsum[bm * 128 + arow0 + mi * 16 + quad * 4 + r],
                          esum[mi][r]);
    }
}

// ---------------------------------------------------------------------------
// Kernel 3: out = 0.5*distill + 0.5*retrieval
// ---------------------------------------------------------------------------
__global__ void __launch_bounds__(256) finalize_kernel(
    const float* __restrict__ rowsum, const float* __restrict__ scal,
    float* __restrict__ out)
{
    const int t = threadIdx.x;
    float ls = 0.f;
    for (int i = t; i < B_ROWS; i += 256) ls += logf(rowsum[i]);
    #pragma unroll
    for (int m = 1; m <= 32; m <<= 1) ls += __shfl_xor(ls, m);
    __shared__ float red[4];
    if ((t & 63) == 0) red[t >> 6] = ls;
    __syncthreads();
    if (t == 0) {
        float total = red[0] + red[1] + red[2] + red[3];
        const float inv_bd = 1.0f / ((float)B_ROWS * (float)D_DIM);
        float distill   = 0.5f * (scal[0] + scal[1]) * inv_bd;
        float retrieval = (total - scal[2]) / (float)B_ROWS;
        out[0] = 0.5f * distill + 0.5f * retrieval;
    }
}

extern "C" void kernel_launch(void* const* d_in, const int* in_sizes, int n_in,
                              void* d_out, int out_size, void* d_ws, size_t ws_size,
                              hipStream_t stream) {
    const float* sq = (const float*)d_in[0];
    const float* sp = (const float*)d_in[1];
    const float* tq = (const float*)d_in[2];
    const float* tp = (const float*)d_in[3];

    char* ws = (char*)d_ws;
    float* rowsum = (float*)ws;                    // 32768 B
    float* scal   = (float*)(ws + 32768);          // 12 B
    u16*   qn     = (u16*)(ws + 65536);            // 16 MiB
    u16*   pn     = (u16*)(ws + 65536 + (size_t)B_ROWS * D_DIM * 2);

    hipMemsetAsync(d_ws, 0, 32768 + 64, stream);
    prep_kernel<<<B_ROWS, 256, 0, stream>>>(sq, sp, tq, tp, qn, pn, scal);
    gemm_rowsum_kernel<<<dim3(64, 64), 256, 0, stream>>>(qn, pn, rowsum);
    finalize_kernel<<<1, 256, 0, stream>>>(rowsum, scal, (float*)d_out);
}

// Round 2
// 330.101 us; speedup vs baseline: 2.0175x; 2.0175x over previous
//
#include <hip/hip_runtime.h>
#include <hip/hip_bf16.h>

typedef unsigned short u16;
typedef short short8 __attribute__((ext_vector_type(8)));
typedef float f32x4 __attribute__((ext_vector_type(4)));

#define B_ROWS 8192
#define D_DIM  1024

// ---------------------------------------------------------------------------
// Workspace layout (bytes):
//   [0,      32768)   ppq[8192]  per-row |q|^2-path partial: sum (sq-tq)^2 ... see prep
//   [32768,  65536)   ppp[8192]
//   [65536,  98304)   ppd[8192]  per-row diag cosine
//   [98304,  98432)   lsp[32]    per-block log-sum partials from reduce_kernel
//   [131072, +4MiB)   gpart[128][8192]  per-(2*bn + wavehalf) row exp-sum partials
//   [131072+4MiB, +16MiB)  qn bf16 [8192][1024]
//   [... +16MiB)           pn bf16 [8192][1024]
// No pre-zeroing required: every cell is written before it is read.
// ---------------------------------------------------------------------------

__device__ __forceinline__ u16 f2bf(float x) {
    union { float f; unsigned u; } v; v.f = x;
    unsigned r = v.u + 0x7fffu + ((v.u >> 16) & 1u);  // RNE
    return (u16)(r >> 16);
}

// ---------------------------------------------------------------------------
// Kernel 1: per-row norms, MSE partials, diag partial, bf16 normalized writes
// grid = 8192 blocks of 256 threads; each thread owns one float4 (D/4 = 256)
// No global atomics: thread 0 stores per-row partials (reduced later).
// ---------------------------------------------------------------------------
__global__ void __launch_bounds__(256) prep_kernel(
    const float* __restrict__ sq, const float* __restrict__ sp,
    const float* __restrict__ tq, const float* __restrict__ tp,
    u16* __restrict__ qn, u16* __restrict__ pn,
    float* __restrict__ ppq, float* __restrict__ ppp, float* __restrict__ ppd)
{
    const int r = blockIdx.x;
    const int t = threadIdx.x;
    const size_t base4 = (size_t)r * (D_DIM / 4) + t;

    const float4 q = ((const float4*)sq)[base4];
    const float4 p = ((const float4*)sp)[base4];
    const float4 a = ((const float4*)tq)[base4];
    const float4 b = ((const float4*)tp)[base4];

    float sq2 = q.x*q.x + q.y*q.y + q.z*q.z + q.w*q.w;
    float sp2 = p.x*p.x + p.y*p.y + p.z*p.z + p.w*p.w;
    float dqx = q.x-a.x, dqy = q.y-a.y, dqz = q.z-a.z, dqw = q.w-a.w;
    float dq  = dqx*dqx + dqy*dqy + dqz*dqz + dqw*dqw;
    float dpx = p.x-b.x, dpy = p.y-b.y, dpz = p.z-b.z, dpw = p.w-b.w;
    float dp  = dpx*dpx + dpy*dpy + dpz*dpz + dpw*dpw;
    float qp  = q.x*p.x + q.y*p.y + q.z*p.z + q.w*p.w;

    // wave64 butterfly reduce (5 values, independent chains -> pipelined)
    #pragma unroll
    for (int m = 1; m <= 32; m <<= 1) {
        sq2 += __shfl_xor(sq2, m);
        sp2 += __shfl_xor(sp2, m);
        dq  += __shfl_xor(dq, m);
        dp  += __shfl_xor(dp, m);
        qp  += __shfl_xor(qp, m);
    }

    __shared__ float red[4][5];
    const int wave = t >> 6, lane = t & 63;
    if (lane == 0) {
        red[wave][0] = sq2; red[wave][1] = sp2;
        red[wave][2] = dq;  red[wave][3] = dp; red[wave][4] = qp;
    }
    __syncthreads();

    // every thread computes the row norms itself (no second barrier)
    const float S0 = red[0][0] + red[1][0] + red[2][0] + red[3][0];
    const float S1 = red[0][1] + red[1][1] + red[2][1] + red[3][1];
    const float rq = 1.0f / fmaxf(sqrtf(S0), 1e-8f);
    const float rp = 1.0f / fmaxf(sqrtf(S1), 1e-8f);

    if (t == 0) {
        float S2 = red[0][2] + red[1][2] + red[2][2] + red[3][2];
        float S3 = red[0][3] + red[1][3] + red[2][3] + red[3][3];
        float S4 = red[0][4] + red[1][4] + red[2][4] + red[3][4];
        ppq[r] = S2;
        ppp[r] = S3;
        ppd[r] = S4 * rq * rp;   // exact fp32 diagonal cosine
    }

    ushort4 qo, po;
    qo.x = f2bf(q.x * rq); qo.y = f2bf(q.y * rq);
    qo.z = f2bf(q.z * rq); qo.w = f2bf(q.w * rq);
    po.x = f2bf(p.x * rp); po.y = f2bf(p.y * rp);
    po.z = f2bf(p.z * rp); po.w = f2bf(p.w * rp);
    ((ushort4*)qn)[base4] = qo;
    ((ushort4*)pn)[base4] = po;
}

// ---------------------------------------------------------------------------
// Kernel 2: S = Qn @ Pn^T (bf16 MFMA 16x16x32), epilogue exp + row partial
// 128x128 tile per block, BK=64, 256 threads = 4 waves in 2x2 arrangement.
// LDS chunk XOR-swizzle: LDS[row][c] holds global k-chunk (c ^ (row&7)).
// Epilogue: plain stores into gpart[2*bn + (wave&1)][row] -- no atomics.
// ---------------------------------------------------------------------------
__global__ void __launch_bounds__(256) gemm_rowsum_kernel(
    const u16* __restrict__ Q, const u16* __restrict__ P,
    float* __restrict__ gpart)
{
    __shared__ u16 smA[128 * 64];   // 16 KiB, row stride 64 elems (128 B)
    __shared__ u16 smB[128 * 64];

    const int tid  = threadIdx.x;
    const int wave = tid >> 6;
    const int lane = tid & 63;
    const int bm = blockIdx.y;
    const int bn = blockIdx.x;

    // staging: each global_load_lds covers 8 rows x 64 k-elems (1 KiB)
    const int lrow   = lane >> 3;               // row within 8-row chunk
    const int gchunk = (lane & 7) ^ lrow;       // XOR swizzle of 16B k-chunks
    const u16* Ag = Q + ((size_t)bm * 128) * D_DIM + gchunk * 8;
    const u16* Bg = P + ((size_t)bn * 128) * D_DIM + gchunk * 8;

    const int quad  = lane >> 4;
    const int rw    = lane & 15;
    const int swz   = lane & 7;                 // == row&7 for fragment rows
    const int arow0 = (wave >> 1) * 64;         // wave's row strip in tile
    const int bcol0 = (wave & 1) * 64;          // wave's col strip in tile

    f32x4 acc[4][4];
    #pragma unroll
    for (int i = 0; i < 4; ++i)
        #pragma unroll
        for (int j = 0; j < 4; ++j)
            acc[i][j] = (f32x4){0.f, 0.f, 0.f, 0.f};

    for (int k0 = 0; k0 < D_DIM; k0 += 64) {
        #pragma unroll
        for (int i = 0; i < 4; ++i) {
            const int r0 = wave * 32 + i * 8;
            __builtin_amdgcn_global_load_lds(
                (const __attribute__((address_space(1))) void*)(Ag + (size_t)(r0 + lrow) * D_DIM + k0),
                (__attribute__((address_space(3))) void*)(smA + r0 * 64), 16, 0, 0);
            __builtin_amdgcn_global_load_lds(
                (const __attribute__((address_space(1))) void*)(Bg + (size_t)(r0 + lrow) * D_DIM + k0),
                (__attribute__((address_space(3))) void*)(smB + r0 * 64), 16, 0, 0);
        }
        __syncthreads();

        #pragma unroll
        for (int kk = 0; kk < 2; ++kk) {
            const int kb = kk * 4;
            const int ch = (((kb + quad) ^ swz)) * 8;   // element offset in row
            short8 afrag[4], bfrag[4];
            #pragma unroll
            for (int mi = 0; mi < 4; ++mi)
                afrag[mi] = *(const short8*)(smA + (arow0 + mi * 16 + rw) * 64 + ch);
            #pragma unroll
            for (int ni = 0; ni < 4; ++ni)
                bfrag[ni] = *(const short8*)(smB + (bcol0 + ni * 16 + rw) * 64 + ch);
            #pragma unroll
            for (int mi = 0; mi < 4; ++mi)
                #pragma unroll
                for (int ni = 0; ni < 4; ++ni)
                    acc[mi][ni] = __builtin_amdgcn_mfma_f32_16x16x32_bf16(
                        afrag[mi], bfrag[ni], acc[mi][ni], 0, 0, 0);
        }
        __syncthreads();
    }

    // epilogue: per-row sum of exp over this wave's 64 columns.
    // C/D layout: col = lane&15, row = quad*4 + reg  (within each 16x16 tile)
    float esum[4][4];
    #pragma unroll
    for (int mi = 0; mi < 4; ++mi)
        #pragma unroll
        for (int r = 0; r < 4; ++r) {
            float s = 0.f;
            #pragma unroll
            for (int ni = 0; ni < 4; ++ni) s += __expf(acc[mi][ni][r]);
            esum[mi][r] = s;
        }
    #pragma unroll
    for (int m = 1; m <= 8; m <<= 1)
        #pragma unroll
        for (int mi = 0; mi < 4; ++mi)
            #pragma unroll
            for (int r = 0; r < 4; ++r)
                esum[mi][r] += __shfl_xor(esum[mi][r], m);

    // waves 0,2 -> slice 2*bn ; waves 1,3 -> slice 2*bn+1 (disjoint rows)
    if (rw == 0) {
        float* dst = gpart + ((size_t)(bn * 2 + (wave & 1))) * B_ROWS
                   + bm * 128 + arow0;
        #pragma unroll
        for (int mi = 0; mi < 4; ++mi)
            #pragma unroll
            for (int r = 0; r < 4; ++r)
                dst[mi * 16 + quad * 4 + r] = esum[mi][r];
    }
}

// ---------------------------------------------------------------------------
// Kernel 3: per-row sum of 128 gpart slices -> log -> per-block partial
// grid = 32 blocks x 256 threads, thread = row (coalesced slice reads)
// ---------------------------------------------------------------------------
__global__ void __launch_bounds__(256) reduce_kernel(
    const float* __restrict__ gpart, float* __restrict__ lsp)
{
    const int r = blockIdx.x * 256 + threadIdx.x;
    float s = 0.f;
    #pragma unroll 8
    for (int j = 0; j < 128; ++j) s += gpart[(size_t)j * B_ROWS + r];
    float ls = logf(s);
    #pragma unroll
    for (int m = 1; m <= 32; m <<= 1) ls += __shfl_xor(ls, m);
    __shared__ float red[4];
    const int t = threadIdx.x;
    if ((t & 63) == 0) red[t >> 6] = ls;
    __syncthreads();
    if (t == 0) lsp[blockIdx.x] = red[0] + red[1] + red[2] + red[3];
}

// ---------------------------------------------------------------------------
// Kernel 4: final scalar combine
// ---------------------------------------------------------------------------
__global__ void __launch_bounds__(256) finalize_kernel(
    const float* __restrict__ ppq, const float* __restrict__ ppp,
    const float* __restrict__ ppd, const float* __restrict__ lsp,
    float* __restrict__ out)
{
    const int t = threadIdx.x;
    float s2 = 0.f, s3 = 0.f, s4 = 0.f;
    for (int i = t; i < B_ROWS; i += 256) {
        s2 += ppq[i]; s3 += ppp[i]; s4 += ppd[i];
    }
    float lt = (t < 32) ? lsp[t] : 0.f;
    #pragma unroll
    for (int m = 1; m <= 32; m <<= 1) {
        s2 += __shfl_xor(s2, m);
        s3 += __shfl_xor(s3, m);
        s4 += __shfl_xor(s4, m);
        lt += __shfl_xor(lt, m);
    }
    __shared__ float red[4][4];
    if ((t & 63) == 0) {
        red[t >> 6][0] = s2; red[t >> 6][1] = s3;
        red[t >> 6][2] = s4; red[t >> 6][3] = lt;
    }
    __syncthreads();
    if (t == 0) {
        float S2 = red[0][0] + red[1][0] + red[2][0] + red[3][0];
        float S3 = red[0][1] + red[1][1] + red[2][1] + red[3][1];
        float S4 = red[0][2] + red[1][2] + red[2][2] + red[3][2];
        float LT = red[0][3] + red[1][3] + red[2][3] + red[3][3];
        const float inv_bd = 1.0f / ((float)B_ROWS * (float)D_DIM);
        float distill   = 0.5f * (S2 + S3) * inv_bd;
        float retrieval = (LT - S4) / (float)B_ROWS;
        out[0] = 0.5f * distill + 0.5f * retrieval;
    }
}

extern "C" void kernel_launch(void* const* d_in, const int* in_sizes, int n_in,
                              void* d_out, int out_size, void* d_ws, size_t ws_size,
                              hipStream_t stream) {
    const float* sq = (const float*)d_in[0];
    const float* sp = (const float*)d_in[1];
    const float* tq = (const float*)d_in[2];
    const float* tp = (const float*)d_in[3];

    char* ws = (char*)d_ws;
    float* ppq   = (float*)(ws);
    float* ppp   = (float*)(ws + 32768);
    float* ppd   = (float*)(ws + 65536);
    float* lsp   = (float*)(ws + 98304);
    float* gpart = (float*)(ws + 131072);                       // 4 MiB
    u16*   qn    = (u16*)(ws + 131072 + (size_t)128 * B_ROWS * 4);
    u16*   pn    = (u16*)((char*)qn + (size_t)B_ROWS * D_DIM * 2);

    prep_kernel<<<B_ROWS, 256, 0, stream>>>(sq, sp, tq, tp, qn, pn, ppq, ppp, ppd);
    gemm_rowsum_kernel<<<dim3(64, 64), 256, 0, stream>>>(qn, pn, gpart);
    reduce_kernel<<<32, 256, 0, stream>>>(gpart, lsp);
    finalize_kernel<<<1, 256, 0, stream>>>(ppq, ppp, ppd, lsp, (float*)d_out);
}

// Round 3
// 253.460 us; speedup vs baseline: 2.6275x; 1.3024x over previous
//
#include <hip/hip_runtime.h>
#include <hip/hip_bf16.h>

typedef unsigned short u16;
typedef unsigned char u8;
typedef float f32x4 __attribute__((ext_vector_type(4)));
typedef int int4v __attribute__((ext_vector_type(4)));
typedef int int8v __attribute__((ext_vector_type(8)));

#define B_ROWS 8192
#define D_DIM  1024
#define FP8_SCALE 16.0f          // store x*16 in e4m3; acc = 256 * s_true
#define ACC_UNSCALE (1.0f/256.0f)

// ---------------------------------------------------------------------------
// Workspace layout (bytes):
//   [0,      32768)   ppq[8192]   per-row MSE(q) partial
//   [32768,  65536)   ppp[8192]   per-row MSE(p) partial
//   [65536,  98304)   ppd[8192]   per-row diag cosine (exact fp32)
//   [98304,  98432)   lsp[32]     per-block log-sum partials
//   [131072, +4MiB)   gpart[128][8192]  per-(2*bn+wavehalf) row exp-sum partials
//   [+4MiB,  +8MiB)   qn fp8 [8192][1024]   (x16 pre-scaled e4m3)
//   [+8MiB,  +8MiB)   pn fp8 [8192][1024]
// No pre-zeroing required: every cell is written before it is read.
// ---------------------------------------------------------------------------

// ---------------------------------------------------------------------------
// Kernel 1: per-row norms, MSE partials, diag partial, fp8 normalized writes
// ---------------------------------------------------------------------------
__global__ void __launch_bounds__(256) prep_kernel(
    const float* __restrict__ sq, const float* __restrict__ sp,
    const float* __restrict__ tq, const float* __restrict__ tp,
    int* __restrict__ qn, int* __restrict__ pn,
    float* __restrict__ ppq, float* __restrict__ ppp, float* __restrict__ ppd)
{
    const int r = blockIdx.x;
    const int t = threadIdx.x;
    const size_t base4 = (size_t)r * (D_DIM / 4) + t;

    const float4 q = ((const float4*)sq)[base4];
    const float4 p = ((const float4*)sp)[base4];
    const float4 a = ((const float4*)tq)[base4];
    const float4 b = ((const float4*)tp)[base4];

    float sq2 = q.x*q.x + q.y*q.y + q.z*q.z + q.w*q.w;
    float sp2 = p.x*p.x + p.y*p.y + p.z*p.z + p.w*p.w;
    float dqx = q.x-a.x, dqy = q.y-a.y, dqz = q.z-a.z, dqw = q.w-a.w;
    float dq  = dqx*dqx + dqy*dqy + dqz*dqz + dqw*dqw;
    float dpx = p.x-b.x, dpy = p.y-b.y, dpz = p.z-b.z, dpw = p.w-b.w;
    float dp  = dpx*dpx + dpy*dpy + dpz*dpz + dpw*dpw;
    float qp  = q.x*p.x + q.y*p.y + q.z*p.z + q.w*p.w;

    #pragma unroll
    for (int m = 1; m <= 32; m <<= 1) {
        sq2 += __shfl_xor(sq2, m);
        sp2 += __shfl_xor(sp2, m);
        dq  += __shfl_xor(dq, m);
        dp  += __shfl_xor(dp, m);
        qp  += __shfl_xor(qp, m);
    }

    __shared__ float red[4][5];
    const int wave = t >> 6, lane = t & 63;
    if (lane == 0) {
        red[wave][0] = sq2; red[wave][1] = sp2;
        red[wave][2] = dq;  red[wave][3] = dp; red[wave][4] = qp;
    }
    __syncthreads();

    const float S0 = red[0][0] + red[1][0] + red[2][0] + red[3][0];
    const float S1 = red[0][1] + red[1][1] + red[2][1] + red[3][1];
    const float rq = 1.0f / fmaxf(sqrtf(S0), 1e-8f);
    const float rp = 1.0f / fmaxf(sqrtf(S1), 1e-8f);

    if (t == 0) {
        float S2 = red[0][2] + red[1][2] + red[2][2] + red[3][2];
        float S3 = red[0][3] + red[1][3] + red[2][3] + red[3][3];
        float S4 = red[0][4] + red[1][4] + red[2][4] + red[3][4];
        ppq[r] = S2;
        ppp[r] = S3;
        ppd[r] = S4 * rq * rp;   // exact fp32 diagonal cosine
    }

    const float fq = rq * FP8_SCALE;
    const float fp = rp * FP8_SCALE;
    int pkq = __builtin_amdgcn_cvt_pk_fp8_f32(q.x * fq, q.y * fq, 0, false);
    pkq     = __builtin_amdgcn_cvt_pk_fp8_f32(q.z * fq, q.w * fq, pkq, true);
    int pkp = __builtin_amdgcn_cvt_pk_fp8_f32(p.x * fp, p.y * fp, 0, false);
    pkp     = __builtin_amdgcn_cvt_pk_fp8_f32(p.z * fp, p.w * fp, pkp, true);
    qn[base4] = pkq;
    pn[base4] = pkp;
}

// ---------------------------------------------------------------------------
// Kernel 2: S = Qn @ Pn^T via MX-scaled fp8 MFMA 16x16x128 (unit scales),
// epilogue exp + per-row partial stores. 128x128 tile, BK=128 bytes, 4 waves.
// LDS 16B-chunk XOR swizzle by row&7 (identical to verified bf16 staging).
// ---------------------------------------------------------------------------
__global__ void __launch_bounds__(256) gemm_rowsum_kernel(
    const u8* __restrict__ Q, const u8* __restrict__ P,
    float* __restrict__ gpart)
{
    __shared__ u8 smA[128 * 128];   // 16 KiB, row stride 128 B
    __shared__ u8 smB[128 * 128];

    const int tid  = threadIdx.x;
    const int wave = tid >> 6;
    const int lane = tid & 63;
    const int bm = blockIdx.y;
    const int bn = blockIdx.x;

    // staging: each global_load_lds covers 8 rows x 128 B (1 KiB)
    const int lrow   = lane >> 3;               // row within 8-row chunk
    const int gchunk = (lane & 7) ^ lrow;       // XOR swizzle of 16B chunks
    const u8* Ag = Q + ((size_t)bm * 128) * D_DIM + gchunk * 16;
    const u8* Bg = P + ((size_t)bn * 128) * D_DIM + gchunk * 16;

    const int quad  = lane >> 4;
    const int rw    = lane & 15;
    const int r7    = lane & 7;                 // == row&7 for fragment rows
    const int arow0 = (wave >> 1) * 64;         // wave's row strip in tile
    const int bcol0 = (wave & 1) * 64;          // wave's col strip in tile

    // fragment = global k [32*quad, 32*quad+32) of its row:
    // 16B chunks 2q and 2q+1, stored at positions (2q)^r7 and (2q+1)^r7
    const int off_lo = ((2 * quad) ^ r7) * 16;
    const int off_hi = ((2 * quad + 1) ^ r7) * 16;

    f32x4 acc[4][4];
    #pragma unroll
    for (int i = 0; i < 4; ++i)
        #pragma unroll
        for (int j = 0; j < 4; ++j)
            acc[i][j] = (f32x4){0.f, 0.f, 0.f, 0.f};

    for (int k0 = 0; k0 < D_DIM; k0 += 128) {
        #pragma unroll
        for (int i = 0; i < 4; ++i) {
            const int r0 = wave * 32 + i * 8;
            __builtin_amdgcn_global_load_lds(
                (const __attribute__((address_space(1))) void*)(Ag + (size_t)(r0 + lrow) * D_DIM + k0),
                (__attribute__((address_space(3))) void*)(smA + r0 * 128), 16, 0, 0);
            __builtin_amdgcn_global_load_lds(
                (const __attribute__((address_space(1))) void*)(Bg + (size_t)(r0 + lrow) * D_DIM + k0),
                (__attribute__((address_space(3))) void*)(smB + r0 * 128), 16, 0, 0);
        }
        __syncthreads();

        int8v afrag[4], bfrag[4];
        #pragma unroll
        for (int mi = 0; mi < 4; ++mi) {
            const u8* row = smA + (arow0 + mi * 16 + rw) * 128;
            int4v lo = *(const int4v*)(row + off_lo);
            int4v hi = *(const int4v*)(row + off_hi);
            afrag[mi] = __builtin_shufflevector(lo, hi, 0, 1, 2, 3, 4, 5, 6, 7);
        }
        #pragma unroll
        for (int ni = 0; ni < 4; ++ni) {
            const u8* row = smB + (bcol0 + ni * 16 + rw) * 128;
            int4v lo = *(const int4v*)(row + off_lo);
            int4v hi = *(const int4v*)(row + off_hi);
            bfrag[ni] = __builtin_shufflevector(lo, hi, 0, 1, 2, 3, 4, 5, 6, 7);
        }
        #pragma unroll
        for (int mi = 0; mi < 4; ++mi)
            #pragma unroll
            for (int ni = 0; ni < 4; ++ni)
                acc[mi][ni] = __builtin_amdgcn_mfma_scale_f32_16x16x128_f8f6f4(
                    afrag[mi], bfrag[ni], acc[mi][ni],
                    0, 0,                       // cbsz=fp8, blgp=fp8
                    0, 0x7f7f7f7f,              // scale A = 1.0 (all bytes 127)
                    0, 0x7f7f7f7f);             // scale B = 1.0
        __syncthreads();
    }

    // epilogue: per-row sum of exp over this wave's 64 columns.
    // C/D layout (shape-determined): col = lane&15, row = quad*4 + reg
    float esum[4][4];
    #pragma unroll
    for (int mi = 0; mi < 4; ++mi)
        #pragma unroll
        for (int r = 0; r < 4; ++r) {
            float s = 0.f;
            #pragma unroll
            for (int ni = 0; ni < 4; ++ni)
                s += __expf(acc[mi][ni][r] * ACC_UNSCALE);
            esum[mi][r] = s;
        }
    #pragma unroll
    for (int m = 1; m <= 8; m <<= 1)
        #pragma unroll
        for (int mi = 0; mi < 4; ++mi)
            #pragma unroll
            for (int r = 0; r < 4; ++r)
                esum[mi][r] += __shfl_xor(esum[mi][r], m);

    // waves 0,2 -> slice 2*bn ; waves 1,3 -> slice 2*bn+1 (disjoint rows)
    if (rw == 0) {
        float* dst = gpart + ((size_t)(bn * 2 + (wave & 1))) * B_ROWS
                   + bm * 128 + arow0;
        #pragma unroll
        for (int mi = 0; mi < 4; ++mi)
            #pragma unroll
            for (int r = 0; r < 4; ++r)
                dst[mi * 16 + quad * 4 + r] = esum[mi][r];
    }
}

// ---------------------------------------------------------------------------
// Kernel 3: per-row sum of 128 gpart slices -> log -> per-block partial
// ---------------------------------------------------------------------------
__global__ void __launch_bounds__(256) reduce_kernel(
    const float* __restrict__ gpart, float* __restrict__ lsp)
{
    const int r = blockIdx.x * 256 + threadIdx.x;
    float s = 0.f;
    #pragma unroll 8
    for (int j = 0; j < 128; ++j) s += gpart[(size_t)j * B_ROWS + r];
    float ls = logf(s);
    #pragma unroll
    for (int m = 1; m <= 32; m <<= 1) ls += __shfl_xor(ls, m);
    __shared__ float red[4];
    const int t = threadIdx.x;
    if ((t & 63) == 0) red[t >> 6] = ls;
    __syncthreads();
    if (t == 0) lsp[blockIdx.x] = red[0] + red[1] + red[2] + red[3];
}

// ---------------------------------------------------------------------------
// Kernel 4: final scalar combine
// ---------------------------------------------------------------------------
__global__ void __launch_bounds__(256) finalize_kernel(
    const float* __restrict__ ppq, const float* __restrict__ ppp,
    const float* __restrict__ ppd, const float* __restrict__ lsp,
    float* __restrict__ out)
{
    const int t = threadIdx.x;
    float s2 = 0.f, s3 = 0.f, s4 = 0.f;
    for (int i = t; i < B_ROWS; i += 256) {
        s2 += ppq[i]; s3 += ppp[i]; s4 += ppd[i];
    }
    float lt = (t < 32) ? lsp[t] : 0.f;
    #pragma unroll
    for (int m = 1; m <= 32; m <<= 1) {
        s2 += __shfl_xor(s2, m);
        s3 += __shfl_xor(s3, m);
        s4 += __shfl_xor(s4, m);
        lt += __shfl_xor(lt, m);
    }
    __shared__ float red[4][4];
    if ((t & 63) == 0) {
        red[t >> 6][0] = s2; red[t >> 6][1] = s3;
        red[t >> 6][2] = s4; red[t >> 6][3] = lt;
    }
    __syncthreads();
    if (t == 0) {
        float S2 = red[0][0] + red[1][0] + red[2][0] + red[3][0];
        float S3 = red[0][1] + red[1][1] + red[2][1] + red[3][1];
        float S4 = red[0][2] + red[1][2] + red[2][2] + red[3][2];
        float LT = red[0][3] + red[1][3] + red[2][3] + red[3][3];
        const float inv_bd = 1.0f / ((float)B_ROWS * (float)D_DIM);
        float distill   = 0.5f * (S2 + S3) * inv_bd;
        float retrieval = (LT - S4) / (float)B_ROWS;
        out[0] = 0.5f * distill + 0.5f * retrieval;
    }
}

extern "C" void kernel_launch(void* const* d_in, const int* in_sizes, int n_in,
                              void* d_out, int out_size, void* d_ws, size_t ws_size,
                              hipStream_t stream) {
    const float* sq = (const float*)d_in[0];
    const float* sp = (const float*)d_in[1];
    const float* tq = (const float*)d_in[2];
    const float* tp = (const float*)d_in[3];

    char* ws = (char*)d_ws;
    float* ppq   = (float*)(ws);
    float* ppp   = (float*)(ws + 32768);
    float* ppd   = (float*)(ws + 65536);
    float* lsp   = (float*)(ws + 98304);
    float* gpart = (float*)(ws + 131072);                        // 4 MiB
    int*   qn    = (int*)(ws + 131072 + (size_t)128 * B_ROWS * 4);
    int*   pn    = (int*)((char*)qn + (size_t)B_ROWS * D_DIM);

    prep_kernel<<<B_ROWS, 256, 0, stream>>>(sq, sp, tq, tp, qn, pn, ppq, ppp, ppd);
    gemm_rowsum_kernel<<<dim3(64, 64), 256, 0, stream>>>((const u8*)qn, (const u8*)pn, gpart);
    reduce_kernel<<<32, 256, 0, stream>>>(gpart, lsp);
    finalize_kernel<<<1, 256, 0, stream>>>(ppq, ppp, ppd, lsp, (float*)d_out);
}

// Round 4
// 244.110 us; speedup vs baseline: 2.7281x; 1.0383x over previous
//
#include <hip/hip_runtime.h>
#include <hip/hip_bf16.h>

typedef unsigned short u16;
typedef unsigned char u8;
typedef float f32x4 __attribute__((ext_vector_type(4)));
typedef int int4v __attribute__((ext_vector_type(4)));
typedef int int8v __attribute__((ext_vector_type(8)));

#define B_ROWS 8192
#define D_DIM  1024
#define FP8_SCALE 16.0f          // store x*16 in e4m3; acc = 256 * s_true
#define ACC_UNSCALE (1.0f/256.0f)

// ---------------------------------------------------------------------------
// Workspace layout (bytes):
//   [0,      32768)   ppq[8192]   per-row MSE(q) partial
//   [32768,  65536)   ppp[8192]   per-row MSE(p) partial
//   [65536,  98304)   ppd[8192]   per-row diag cosine (exact fp32)
//   [98304,  98816)   bpart[32][4] per-reduce-block {sum_log, sum_ppq, sum_ppp, sum_ppd}
//   [131072, +4MiB)   gpart[128][8192]  per-(2*bn+wavehalf) row exp-sum partials
//   [+4MiB,  +8MiB)   qn fp8 [8192][1024]   (x16 pre-scaled e4m3)
//   [+8MiB,  ...)     pn fp8 [8192][1024]
// No pre-zeroing required: every cell is written before it is read.
// ---------------------------------------------------------------------------

// ---------------------------------------------------------------------------
// Kernel 1: one WAVE per row — no barriers, no LDS, pure butterfly reduce.
// Lane l owns float4s at j-major indices j*64+l (coalesced 16 B/lane).
// grid = 2048 blocks x 256 threads (4 rows/block).
// ---------------------------------------------------------------------------
__global__ void __launch_bounds__(256) prep_kernel(
    const float* __restrict__ sq, const float* __restrict__ sp,
    const float* __restrict__ tq, const float* __restrict__ tp,
    int* __restrict__ qn, int* __restrict__ pn,
    float* __restrict__ ppq, float* __restrict__ ppp, float* __restrict__ ppd)
{
    const int wave = threadIdx.x >> 6;
    const int l    = threadIdx.x & 63;
    const int r    = blockIdx.x * 4 + wave;
    const size_t rb4 = (size_t)r * (D_DIM / 4);

    const float4* Q4 = (const float4*)sq + rb4;
    const float4* P4 = (const float4*)sp + rb4;
    const float4* A4 = (const float4*)tq + rb4;
    const float4* B4 = (const float4*)tp + rb4;

    float4 qv[4], pv[4];
    float sq2 = 0.f, sp2 = 0.f, dq = 0.f, dp = 0.f, qp = 0.f;
    #pragma unroll
    for (int j = 0; j < 4; ++j) {
        const int idx = j * 64 + l;
        float4 q = Q4[idx], p = P4[idx], a = A4[idx], b = B4[idx];
        qv[j] = q; pv[j] = p;
        sq2 += q.x*q.x + q.y*q.y + q.z*q.z + q.w*q.w;
        sp2 += p.x*p.x + p.y*p.y + p.z*p.z + p.w*p.w;
        float dx = q.x-a.x, dy = q.y-a.y, dz = q.z-a.z, dw = q.w-a.w;
        dq += dx*dx + dy*dy + dz*dz + dw*dw;
        dx = p.x-b.x; dy = p.y-b.y; dz = p.z-b.z; dw = p.w-b.w;
        dp += dx*dx + dy*dy + dz*dz + dw*dw;
        qp += q.x*p.x + q.y*p.y + q.z*p.z + q.w*p.w;
    }

    #pragma unroll
    for (int m = 1; m <= 32; m <<= 1) {
        sq2 += __shfl_xor(sq2, m);
        sp2 += __shfl_xor(sp2, m);
        dq  += __shfl_xor(dq, m);
        dp  += __shfl_xor(dp, m);
        qp  += __shfl_xor(qp, m);
    }

    const float rq = 1.0f / fmaxf(sqrtf(sq2), 1e-8f);
    const float rp = 1.0f / fmaxf(sqrtf(sp2), 1e-8f);

    if (l == 0) {
        ppq[r] = dq;
        ppp[r] = dp;
        ppd[r] = qp * rq * rp;   // exact fp32 diagonal cosine
    }

    const float fq = rq * FP8_SCALE;
    const float fp = rp * FP8_SCALE;
    int* qrow = qn + (size_t)r * (D_DIM / 4);
    int* prow = pn + (size_t)r * (D_DIM / 4);
    #pragma unroll
    for (int j = 0; j < 4; ++j) {
        const int idx = j * 64 + l;
        int pk = __builtin_amdgcn_cvt_pk_fp8_f32(qv[j].x * fq, qv[j].y * fq, 0, false);
        pk     = __builtin_amdgcn_cvt_pk_fp8_f32(qv[j].z * fq, qv[j].w * fq, pk, true);
        qrow[idx] = pk;
        pk = __builtin_amdgcn_cvt_pk_fp8_f32(pv[j].x * fp, pv[j].y * fp, 0, false);
        pk = __builtin_amdgcn_cvt_pk_fp8_f32(pv[j].z * fp, pv[j].w * fp, pk, true);
        prow[idx] = pk;
    }
}

// ---------------------------------------------------------------------------
// Kernel 2: S = Qn @ Pn^T via MX-scaled fp8 MFMA 16x16x128 (unit scales),
// epilogue exp + per-row partial stores. 128x128 tile, BK=128 bytes, 4 waves.
// LDS 16B-chunk XOR swizzle by row&7. Fragment reads grouped: all lo-half
// b128s first, then all hi-half b128s (matches the bf16 kernel's
// zero-conflict instruction shape; the lo/hi paired order showed 8
// conflict-cycles per read).
// ---------------------------------------------------------------------------
__global__ void __launch_bounds__(256) gemm_rowsum_kernel(
    const u8* __restrict__ Q, const u8* __restrict__ P,
    float* __restrict__ gpart)
{
    __shared__ u8 smA[128 * 128];   // 16 KiB, row stride 128 B
    __shared__ u8 smB[128 * 128];

    const int tid  = threadIdx.x;
    const int wave = tid >> 6;
    const int lane = tid & 63;
    const int bm = blockIdx.y;
    const int bn = blockIdx.x;

    // staging: each global_load_lds covers 8 rows x 128 B (1 KiB)
    const int lrow   = lane >> 3;               // row within 8-row chunk
    const int gchunk = (lane & 7) ^ lrow;       // XOR swizzle of 16B chunks
    const u8* Ag = Q + ((size_t)bm * 128) * D_DIM + gchunk * 16;
    const u8* Bg = P + ((size_t)bn * 128) * D_DIM + gchunk * 16;

    const int quad  = lane >> 4;
    const int rw    = lane & 15;
    const int r7    = lane & 7;                 // == row&7 for fragment rows
    const int arow0 = (wave >> 1) * 64;         // wave's row strip in tile
    const int bcol0 = (wave & 1) * 64;          // wave's col strip in tile

    // fragment = global k [32*quad, 32*quad+32) of its row:
    // 16B chunks 2q and 2q+1, stored at positions (2q)^r7 and (2q+1)^r7
    const int off_lo = ((2 * quad) ^ r7) * 16;
    const int off_hi = ((2 * quad + 1) ^ r7) * 16;

    f32x4 acc[4][4];
    #pragma unroll
    for (int i = 0; i < 4; ++i)
        #pragma unroll
        for (int j = 0; j < 4; ++j)
            acc[i][j] = (f32x4){0.f, 0.f, 0.f, 0.f};

    for (int k0 = 0; k0 < D_DIM; k0 += 128) {
        #pragma unroll
        for (int i = 0; i < 4; ++i) {
            const int r0 = wave * 32 + i * 8;
            __builtin_amdgcn_global_load_lds(
                (const __attribute__((address_space(1))) void*)(Ag + (size_t)(r0 + lrow) * D_DIM + k0),
                (__attribute__((address_space(3))) void*)(smA + r0 * 128), 16, 0, 0);
            __builtin_amdgcn_global_load_lds(
                (const __attribute__((address_space(1))) void*)(Bg + (size_t)(r0 + lrow) * D_DIM + k0),
                (__attribute__((address_space(3))) void*)(smB + r0 * 128), 16, 0, 0);
        }
        __syncthreads();

        union Frag { int8v v8; struct { int4v lo, hi; } h; };
        Frag af[4], bf[4];
        // group 1: all lo halves (8 consecutive b128, one bank-clean pattern)
        #pragma unroll
        for (int mi = 0; mi < 4; ++mi)
            af[mi].h.lo = *(const int4v*)(smA + (arow0 + mi * 16 + rw) * 128 + off_lo);
        #pragma unroll
        for (int ni = 0; ni < 4; ++ni)
            bf[ni].h.lo = *(const int4v*)(smB + (bcol0 + ni * 16 + rw) * 128 + off_lo);
        __builtin_amdgcn_sched_barrier(0);
        // group 2: all hi halves
        #pragma unroll
        for (int mi = 0; mi < 4; ++mi)
            af[mi].h.hi = *(const int4v*)(smA + (arow0 + mi * 16 + rw) * 128 + off_hi);
        #pragma unroll
        for (int ni = 0; ni < 4; ++ni)
            bf[ni].h.hi = *(const int4v*)(smB + (bcol0 + ni * 16 + rw) * 128 + off_hi);

        #pragma unroll
        for (int mi = 0; mi < 4; ++mi)
            #pragma unroll
            for (int ni = 0; ni < 4; ++ni)
                acc[mi][ni] = __builtin_amdgcn_mfma_scale_f32_16x16x128_f8f6f4(
                    af[mi].v8, bf[ni].v8, acc[mi][ni],
                    0, 0,                       // cbsz=fp8, blgp=fp8
                    0, 0x7f7f7f7f,              // scale A = 1.0
                    0, 0x7f7f7f7f);             // scale B = 1.0
        __syncthreads();
    }

    // epilogue: per-row sum of exp over this wave's 64 columns.
    // C/D layout (shape-determined): col = lane&15, row = quad*4 + reg
    float esum[4][4];
    #pragma unroll
    for (int mi = 0; mi < 4; ++mi)
        #pragma unroll
        for (int r = 0; r < 4; ++r) {
            float s = 0.f;
            #pragma unroll
            for (int ni = 0; ni < 4; ++ni)
                s += __expf(acc[mi][ni][r] * ACC_UNSCALE);
            esum[mi][r] = s;
        }
    #pragma unroll
    for (int m = 1; m <= 8; m <<= 1)
        #pragma unroll
        for (int mi = 0; mi < 4; ++mi)
            #pragma unroll
            for (int r = 0; r < 4; ++r)
                esum[mi][r] += __shfl_xor(esum[mi][r], m);

    // waves 0,2 -> slice 2*bn ; waves 1,3 -> slice 2*bn+1 (disjoint rows)
    if (rw == 0) {
        float* dst = gpart + ((size_t)(bn * 2 + (wave & 1))) * B_ROWS
                   + bm * 128 + arow0;
        #pragma unroll
        for (int mi = 0; mi < 4; ++mi)
            #pragma unroll
            for (int r = 0; r < 4; ++r)
                dst[mi * 16 + quad * 4 + r] = esum[mi][r];
    }
}

// ---------------------------------------------------------------------------
// Kernel 3: per-row sum of 128 gpart slices -> log; fold in the three
// pp-array reductions; one float4 partial per block.
// ---------------------------------------------------------------------------
__global__ void __launch_bounds__(256) reduce_kernel(
    const float* __restrict__ gpart,
    const float* __restrict__ ppq, const float* __restrict__ ppp,
    const float* __restrict__ ppd, float4* __restrict__ bpart)
{
    const int t = threadIdx.x;
    const int r = blockIdx.x * 256 + t;
    float s = 0.f;
    #pragma unroll 8
    for (int j = 0; j < 128; ++j) s += gpart[(size_t)j * B_ROWS + r];
    float ls = logf(s);
    float v2 = ppq[r], v3 = ppp[r], v4 = ppd[r];
    #pragma unroll
    for (int m = 1; m <= 32; m <<= 1) {
        ls += __shfl_xor(ls, m);
        v2 += __shfl_xor(v2, m);
        v3 += __shfl_xor(v3, m);
        v4 += __shfl_xor(v4, m);
    }
    __shared__ float red[4][4];
    if ((t & 63) == 0) {
        red[t >> 6][0] = ls; red[t >> 6][1] = v2;
        red[t >> 6][2] = v3; red[t >> 6][3] = v4;
    }
    __syncthreads();
    if (t == 0) {
        float4 o;
        o.x = red[0][0] + red[1][0] + red[2][0] + red[3][0];
        o.y = red[0][1] + red[1][1] + red[2][1] + red[3][1];
        o.z = red[0][2] + red[1][2] + red[2][2] + red[3][2];
        o.w = red[0][3] + red[1][3] + red[2][3] + red[3][3];
        bpart[blockIdx.x] = o;
    }
}

// ---------------------------------------------------------------------------
// Kernel 4: final scalar combine (1 wave, 32 float4 partials)
// ---------------------------------------------------------------------------
__global__ void __launch_bounds__(64) finalize_kernel(
    const float4* __restrict__ bpart, float* __restrict__ out)
{
    const int t = threadIdx.x;
    float4 v = (t < 32) ? bpart[t] : (float4){0.f, 0.f, 0.f, 0.f};
    #pragma unroll
    for (int m = 1; m <= 16; m <<= 1) {
        v.x += __shfl_xor(v.x, m);
        v.y += __shfl_xor(v.y, m);
        v.z += __shfl_xor(v.z, m);
        v.w += __shfl_xor(v.w, m);
    }
    if (t == 0) {
        const float inv_bd = 1.0f / ((float)B_ROWS * (float)D_DIM);
        float distill   = 0.5f * (v.y + v.z) * inv_bd;
        float retrieval = (v.x - v.w) / (float)B_ROWS;
        out[0] = 0.5f * distill + 0.5f * retrieval;
    }
}

extern "C" void kernel_launch(void* const* d_in, const int* in_sizes, int n_in,
                              void* d_out, int out_size, void* d_ws, size_t ws_size,
                              hipStream_t stream) {
    const float* sq = (const float*)d_in[0];
    const float* sp = (const float*)d_in[1];
    const float* tq = (const float*)d_in[2];
    const float* tp = (const float*)d_in[3];

    char* ws = (char*)d_ws;
    float*  ppq   = (float*)(ws);
    float*  ppp   = (float*)(ws + 32768);
    float*  ppd   = (float*)(ws + 65536);
    float4* bpart = (float4*)(ws + 98304);
    float*  gpart = (float*)(ws + 131072);                        // 4 MiB
    int*    qn    = (int*)(ws + 131072 + (size_t)128 * B_ROWS * 4);
    int*    pn    = (int*)((char*)qn + (size_t)B_ROWS * D_DIM);

    prep_kernel<<<B_ROWS / 4, 256, 0, stream>>>(sq, sp, tq, tp, qn, pn, ppq, ppp, ppd);
    gemm_rowsum_kernel<<<dim3(64, 64), 256, 0, stream>>>((const u8*)qn, (const u8*)pn, gpart);
    reduce_kernel<<<32, 256, 0, stream>>>(gpart, ppq, ppp, ppd, bpart);
    finalize_kernel<<<1, 64, 0, stream>>>(bpart, (float*)d_out);
}